// Round 1
// baseline (10.947 us; speedup 1.0000x reference)
//
#include <hip/hip_runtime.h>

// Reference collapses to: k_i = dot(B_i[:,0], C_i[0,:]) (scalar per layer);
//   s1 = (x*k1 > 0), s2 = (s1*k2 > 0), out = (s2*k3 > 0)   (all as 0.0/1.0 f32)
// A matrices are dead (h_prev == 0 so Ah == 0; spectral clamp affects nothing).
// Purely memory-bound elementwise pass over 4096*1024 f32.

__global__ void __launch_bounds__(256)
isocortex_spike_kernel(const float* __restrict__ x,
                       const float* __restrict__ Bs, const float* __restrict__ Cs,
                       const float* __restrict__ Ba, const float* __restrict__ Ca,
                       const float* __restrict__ Be, const float* __restrict__ Ce,
                       float* __restrict__ out, int n4) {
    // Three 16-element dot products; tiny arrays, L1-broadcast across waves.
    float k1 = 0.f, k2 = 0.f, k3 = 0.f;
#pragma unroll
    for (int s = 0; s < 16; ++s) {
        k1 += Bs[s] * Cs[s];
        k2 += Ba[s] * Ca[s];
        k3 += Be[s] * Ce[s];
    }

    const float4* __restrict__ x4 = reinterpret_cast<const float4*>(x);
    float4* __restrict__ o4 = reinterpret_cast<float4*>(out);

    int idx = blockIdx.x * blockDim.x + threadIdx.x;
    int stride = gridDim.x * blockDim.x;
    for (int i = idx; i < n4; i += stride) {
        float4 v = x4[i];
        float4 r;
        float* vp = reinterpret_cast<float*>(&v);
        float* rp = reinterpret_cast<float*>(&r);
#pragma unroll
        for (int j = 0; j < 4; ++j) {
            float y1 = vp[j] * k1;
            float s1 = (y1 > 0.f) ? 1.f : 0.f;
            float y2 = s1 * k2;
            float s2 = (y2 > 0.f) ? 1.f : 0.f;
            float y3 = s2 * k3;
            rp[j] = (y3 > 0.f) ? 1.f : 0.f;
        }
        o4[i] = r;
    }
}

extern "C" void kernel_launch(void* const* d_in, const int* in_sizes, int n_in,
                              void* d_out, int out_size, void* d_ws, size_t ws_size,
                              hipStream_t stream) {
    // setup_inputs order:
    // 0: incoming_spikes (4096*1024 f32)
    // 1: A_sensory   2: B_sensory (16)   3: C_sensory (16)
    // 4: A_association 5: B_association  6: C_association
    // 7: A_executive   8: B_executive    9: C_executive
    const float* x  = (const float*)d_in[0];
    const float* Bs = (const float*)d_in[2];
    const float* Cs = (const float*)d_in[3];
    const float* Ba = (const float*)d_in[5];
    const float* Ca = (const float*)d_in[6];
    const float* Be = (const float*)d_in[8];
    const float* Ce = (const float*)d_in[9];
    float* out = (float*)d_out;

    int n4 = out_size / 4;  // out_size = 4096*1024, divisible by 4
    int block = 256;
    int grid = (n4 + block - 1) / block;
    if (grid > 2048) grid = 2048;

    isocortex_spike_kernel<<<grid, block, 0, stream>>>(x, Bs, Cs, Ba, Ca, Be, Ce, out, n4);
}